// Round 10
// baseline (697.224 us; speedup 1.0000x reference)
//
#include <hip/hip_runtime.h>
#include <hip/hip_fp16.h>

#define G_ 512
#define B_ 64
#define I_ 32
#define H_ 64
#define NGATE 256  // 4*H

typedef _Float16 half8 __attribute__((ext_vector_type(8)));
typedef _Float16 h4 __attribute__((ext_vector_type(4)));
typedef float f32x4 __attribute__((ext_vector_type(4)));
typedef float f32x2 __attribute__((ext_vector_type(2)));

#if __has_builtin(__builtin_elementwise_fma)
#define PKFMA(a, b, c) __builtin_elementwise_fma((a), (b), (c))  // -> v_pk_fma_f32
#else
__device__ __forceinline__ f32x2 PKFMA(f32x2 a, f32x2 b, f32x2 c) {
  f32x2 r;
  r[0] = __builtin_fmaf(a[0], b[0], c[0]);
  r[1] = __builtin_fmaf(a[1], b[1], c[1]);
  return r;
}
#endif

__device__ __forceinline__ float sigf(float x) {
  return 1.0f / (1.0f + __expf(-x));
}
__device__ __forceinline__ float tanh_fast(float x) {
  x = fminf(fmaxf(x, -15.0f), 15.0f);
  float e = __expf(2.0f * x);
  return (e - 1.0f) / (e + 1.0f);
}

// ---------------- K1: xproj[b][g][col*4+q]  (coalesced; scan reads one h4/lane)
__global__ __launch_bounds__(256) void k_xproj(
    const float* __restrict__ input, const float* __restrict__ W_ih,
    const float* __restrict__ b_ih, const float* __restrict__ b_hh,
    _Float16* __restrict__ xproj) {
  const int g = blockIdx.x;
  const int t = threadIdx.x;
  const int col = t >> 2;
  const int q = t & 3;
  const int row = q * H_ + col;  // gate-row in torch i,f,g,o order
  __shared__ alignas(16) float inp[B_ * I_];
  const float* ing = input + (size_t)g * (B_ * I_);
#pragma unroll
  for (int u = 0; u < (B_ * I_) / 256; ++u) inp[u * 256 + t] = ing[u * 256 + t];
  float w[I_];
#pragma unroll
  for (int k = 0; k < I_; k += 4) {
    f32x4 v = *(const f32x4*)(W_ih + (size_t)row * I_ + k);
    w[k] = v[0]; w[k + 1] = v[1]; w[k + 2] = v[2]; w[k + 3] = v[3];
  }
  const float bias = b_ih[row] + b_hh[row];
  __syncthreads();
  for (int b = 0; b < B_; ++b) {
    float a0 = bias, a1 = 0.f, a2 = 0.f, a3 = 0.f;
#pragma unroll
    for (int k = 0; k < I_; k += 4) {
      f32x4 iv = *(const f32x4*)&inp[b * I_ + k];
      a0 += iv[0] * w[k]; a1 += iv[1] * w[k + 1];
      a2 += iv[2] * w[k + 2]; a3 += iv[3] * w[k + 3];
    }
    xproj[((size_t)b * G_ + g) * NGATE + t] = (_Float16)((a0 + a1) + (a2 + a3));
  }
}

// ---------------- scan body: f32 weights in VGPRs + v_pk_fma_f32 dots.
// v_dot2_f32_f16 is ~quarter-rate (R7: 8 cyc/inst measured); packed fp32 FMA
// is full-rate (it's the basis of the 157 TF fp32 spec). W = 4x32 f32x2 =
// 256 VGPR (launch_bounds(64,1) -> ~1 wave/SIMD, which is all we need:
// 64 independent waves on 64 CUs). h recurrence kept in f32 LDS (precision up).
__device__ __forceinline__ void scan_row(
    int b, int j, const _Float16* __restrict__ xproj,
    const float* __restrict__ h0, const float* __restrict__ c0,
    const float* __restrict__ W_hh, _Float16* __restrict__ hs,
    float* hsh) {
  f32x2 w[4][32];
#pragma unroll
  for (int q = 0; q < 4; ++q) {
    const f32x4* wr = (const f32x4*)(W_hh + (size_t)(q * H_ + j) * H_);
#pragma unroll
    for (int kk = 0; kk < 16; ++kk) {
      f32x4 v = wr[kk];
      w[q][2 * kk] = f32x2{v[0], v[1]};
      w[q][2 * kk + 1] = f32x2{v[2], v[3]};
    }
  }
  float c = c0[b * H_ + j];
  hsh[j] = h0[b * H_ + j];

  const h4* xrow = (const h4*)(xproj + (size_t)b * G_ * NGATE) + j;
  h4 p[8];
#pragma unroll
  for (int d = 0; d < 8; ++d) p[d] = xrow[(size_t)d * 64];

  _Float16* hrow = hs + (size_t)b * (G_ * H_) + j;

  for (int g0 = 0; g0 < G_; g0 += 8) {
#pragma unroll
    for (int d = 0; d < 8; ++d) {
      const int g = g0 + d;
      f32x2 a[4], a2[4];
#pragma unroll
      for (int q = 0; q < 4; ++q) {
        a[q] = f32x2{(float)p[d][q], 0.0f};
        a2[q] = f32x2{0.0f, 0.0f};
      }
      const f32x4* hp4 = (const f32x4*)hsh;
#pragma unroll
      for (int k4 = 0; k4 < 8; ++k4) {
        f32x4 hv = hp4[k4];
        f32x2 lo = f32x2{hv[0], hv[1]};
        f32x2 hi = f32x2{hv[2], hv[3]};
#pragma unroll
        for (int q = 0; q < 4; ++q) {
          a[q] = PKFMA(w[q][2 * k4], lo, a[q]);
          a2[q] = PKFMA(w[q][2 * k4 + 1], hi, a2[q]);
        }
      }
#pragma unroll
      for (int k4 = 8; k4 < 16; ++k4) {
        f32x4 hv = hp4[k4];
        f32x2 lo = f32x2{hv[0], hv[1]};
        f32x2 hi = f32x2{hv[2], hv[3]};
#pragma unroll
        for (int q = 0; q < 4; ++q) {
          a[q] = PKFMA(w[q][2 * k4], lo, a[q]);
          a2[q] = PKFMA(w[q][2 * k4 + 1], hi, a2[q]);
        }
      }
      float gate[4];
#pragma unroll
      for (int q = 0; q < 4; ++q) {
        f32x2 s = a[q] + a2[q];
        gate[q] = s[0] + s[1];
      }

      float ig = sigf(gate[0]);
      float fg = sigf(gate[1]);
      float gg = tanh_fast(gate[2]);
      float og = sigf(gate[3]);
      c = fg * c + ig * gg;
      float hh = og * tanh_fast(c);
      hsh[j] = hh;  // in-order LDS within the wave orders this vs next reads
      hrow[(size_t)g * H_] = (_Float16)hh;
      if (g + 8 < G_) p[d] = xrow[(size_t)(g + 8) * 64];
    }
  }
}

// ---------------- f32 -> f16 streaming convert (vec8 per thread-iter)
__device__ __forceinline__ void conv_loop(
    const float* __restrict__ src, _Float16* __restrict__ dst, int nvec,
    int gtid, int gstride) {
  for (int i = gtid; i < nvec; i += gstride) {
    const f32x4* s = (const f32x4*)(src + (size_t)i * 8);
    f32x4 v0 = s[0];
    f32x4 v1 = s[1];
    half8 h;
    h[0] = (_Float16)v0[0]; h[1] = (_Float16)v0[1];
    h[2] = (_Float16)v0[2]; h[3] = (_Float16)v0[3];
    h[4] = (_Float16)v1[0]; h[5] = (_Float16)v1[1];
    h[6] = (_Float16)v1[2]; h[7] = (_Float16)v1[3];
    *(half8*)(dst + (size_t)i * 8) = h;
  }
}

#define NCONV 768  // fewer convert waves -> less issue-slot theft from scan CUs

// ---------------- K2: fused scan (blocks 0-63) + weight convert (blocks 64+)
__global__ __launch_bounds__(64, 1) void k_scan_conv(
    const _Float16* __restrict__ xproj, const float* __restrict__ h0,
    const float* __restrict__ c0, const float* __restrict__ W_hh,
    _Float16* __restrict__ hs,
    const float* __restrict__ W1, _Float16* __restrict__ W1h,
    const float* __restrict__ W2, _Float16* __restrict__ W2h,
    const float* __restrict__ W3, _Float16* __restrict__ W3h) {
  __shared__ alignas(16) float hsh[H_];
  const int bid = blockIdx.x;
  if (bid < B_) {
    scan_row(bid, threadIdx.x, xproj, h0, c0, W_hh, hs, hsh);
    return;
  }
  const int gtid = (bid - B_) * 64 + threadIdx.x;
  const int gstride = NCONV * 64;
  conv_loop(W1, W1h, (5120 * 32768) / 8, gtid, gstride);
  conv_loop(W2, W2h, (2560 * 5120) / 8, gtid, gstride);
  conv_loop(W3, W3h, (512 * 2560) / 8, gtid, gstride);
}

// ---------------- LDS-staged GEMM on f16 weights (round-9 proven).
template <int N, int K, int KC, int NTILES, int KW>
__global__ __launch_bounds__(256) void k_gemm_h(
    const _Float16* __restrict__ X, const _Float16* __restrict__ Wh,
    float* __restrict__ part) {
  constexpr int ROWB = KW * 2;
  constexpr int SLOTS = ROWB / 16;
  constexpr int RPP = 64 / SLOTS;
  constexpr int NPASS = 16 / RPP;
  static_assert(KC % KW == 0, "stage divisibility");
  __shared__ alignas(16) _Float16 wl[64 * KW];
  const int bid = blockIdx.x;
  const int n0 = (bid % NTILES) * 64;
  const int ks = bid / NTILES;
  const int kbeg = ks * KC;
  const int lane = threadIdx.x & 63;
  const int wave = threadIdx.x >> 6;
  const int r = lane & 15;
  const int gq = lane >> 4;
  const int s = lane % SLOTS;
  const int ro = lane / SLOTS;

  const _Float16* xrow = X + (size_t)r * K + kbeg + 8 * gq;
  f32x4 acc[4] = {};

  for (int st = 0; st < KC / KW; ++st) {
    const int kst = kbeg + st * KW;
#pragma unroll
    for (int pass = 0; pass < NPASS; ++pass) {
      const int rr = wave * 16 + pass * RPP + ro;
      half8 hv = *(const half8*)(Wh + (size_t)(n0 + rr) * K + kst + s * 8);
      int byte = rr * ROWB + s * 16;
      byte ^= (rr & 7) << 4;
      *(half8*)((char*)wl + byte) = hv;
    }
    __syncthreads();
#pragma unroll
    for (int k32 = 0; k32 < KW; k32 += 32) {
      int rbyte = (wave * 16 + r) * ROWB + (k32 + 8 * gq) * 2;
      rbyte ^= (r & 7) << 4;
      half8 bfv = *(const half8*)((const char*)wl + rbyte);
      const _Float16* xp = xrow + st * KW + k32;
#pragma unroll
      for (int mi = 0; mi < 4; ++mi) {
        half8 af = *(const half8*)(xp + (size_t)(mi * 16) * K);
        acc[mi] = __builtin_amdgcn_mfma_f32_16x16x32_f16(af, bfv, acc[mi], 0, 0, 0);
      }
    }
    __syncthreads();
  }
#pragma unroll
  for (int mi = 0; mi < 4; ++mi) {
#pragma unroll
    for (int q = 0; q < 4; ++q) {
      int row = mi * 16 + gq * 4 + q;
      part[((size_t)ks * 64 + row) * N + n0 + wave * 16 + r] = acc[mi][q];
    }
  }
}

// ---------------- reduce k-split partials + bias -> f16 activations (x4 vectorized)
template <int N, int KS>
__global__ __launch_bounds__(256) void k_reduce(
    const float* __restrict__ part, const float* __restrict__ bias,
    _Float16* __restrict__ out) {
  const int idx4 = (blockIdx.x * 256 + threadIdx.x) * 4;
  const int n = idx4 % N;
  f32x4 s = *(const f32x4*)(bias + n);
#pragma unroll
  for (int ks = 0; ks < KS; ++ks) s += *(const f32x4*)(part + (size_t)ks * 64 * N + idx4);
#pragma unroll
  for (int t = 0; t < 4; ++t) out[idx4 + t] = (_Float16)s[t];
}

// ---------------- final reduce + bias + sigmoid -> fp32 output
template <int N, int KS>
__global__ __launch_bounds__(256) void k_reduce_sig(
    const float* __restrict__ part, const float* __restrict__ bias,
    float* __restrict__ out) {
  const int idx4 = (blockIdx.x * 256 + threadIdx.x) * 4;
  const int n = idx4 % N;
  f32x4 s = *(const f32x4*)(bias + n);
#pragma unroll
  for (int ks = 0; ks < KS; ++ks) s += *(const f32x4*)(part + (size_t)ks * 64 * N + idx4);
#pragma unroll
  for (int t = 0; t < 4; ++t) out[idx4 + t] = sigf(s[t]);
}

extern "C" void kernel_launch(void* const* d_in, const int* in_sizes, int n_in,
                              void* d_out, int out_size, void* d_ws, size_t ws_size,
                              hipStream_t stream) {
  const float* input = (const float*)d_in[0];
  const float* h0    = (const float*)d_in[1];
  const float* c0    = (const float*)d_in[2];
  const float* W_ih  = (const float*)d_in[3];
  const float* W_hh  = (const float*)d_in[4];
  const float* b_ih  = (const float*)d_in[5];
  const float* b_hh  = (const float*)d_in[6];
  const float* W1    = (const float*)d_in[7];
  const float* b1    = (const float*)d_in[8];
  const float* W2    = (const float*)d_in[9];
  const float* b2    = (const float*)d_in[10];
  const float* W3    = (const float*)d_in[11];
  const float* b3    = (const float*)d_in[12];
  float* out = (float*)d_out;

  // Workspace layout (~411.5 MB of ~2.6 GB):
  //   [0, 41943040)              part; xproj overlay (16.8 MB)
  //   [41943040, 46137344)       hs_f16  [64][32768]
  //   [46137344, 46792704)       x2_f16  [64][5120]
  //   [46792704, 47120384)       x3_f16  [64][2560]
  //   [47120384, 382664704)      W1h f16 [5120][32768]
  //   [382664704, 408879104)     W2h f16 [2560][5120]
  //   [408879104, 411500544)     W3h f16 [512][2560]
  uint8_t* ws = (uint8_t*)d_ws;
  float*    part  = (float*)ws;
  _Float16* xproj = (_Float16*)ws;
  _Float16* hs    = (_Float16*)(ws + 41943040);
  _Float16* x2    = (_Float16*)(ws + 46137344);
  _Float16* x3    = (_Float16*)(ws + 46792704);
  _Float16* W1h   = (_Float16*)(ws + 47120384);
  _Float16* W2h   = (_Float16*)(ws + 382664704);
  _Float16* W3h   = (_Float16*)(ws + 408879104);

  k_xproj<<<G_, 256, 0, stream>>>(input, W_ih, b_ih, b_hh, xproj);
  // Fused: blocks 0-63 = pk-fma scan (1 wave each); blocks 64.. = f32->f16 convert
  k_scan_conv<<<B_ + NCONV, 64, 0, stream>>>(xproj, h0, c0, W_hh, hs,
                                             W1, W1h, W2, W2h, W3, W3h);
  // GEMM1: [64,32768] x W1h[5120,32768]^T, ksplit=32 (KC=1024), KW=256
  k_gemm_h<5120, 32768, 1024, 80, 256><<<80 * 32, 256, 0, stream>>>(hs, W1h, part);
  k_reduce<5120, 32><<<(64 * 5120) / 4 / 256, 256, 0, stream>>>(part, b1, x2);
  // GEMM2: [64,5120] x W2h[2560,5120]^T, ksplit=8 (KC=640), KW=128
  k_gemm_h<2560, 5120, 640, 40, 128><<<40 * 8, 256, 0, stream>>>(x2, W2h, part);
  k_reduce<2560, 8><<<(64 * 2560) / 4 / 256, 256, 0, stream>>>(part, b2, x3);
  // GEMM3: [64,2560] x W3h[512,2560]^T, ksplit=10 (KC=256), KW=128
  k_gemm_h<512, 2560, 256, 8, 128><<<8 * 10, 256, 0, stream>>>(x3, W3h, part);
  k_reduce_sig<512, 10><<<(64 * 512) / 4 / 256, 256, 0, stream>>>(part, b3, out);
}

// Round 11
// 497.602 us; speedup vs baseline: 1.4012x; 1.4012x over previous
//
#include <hip/hip_runtime.h>
#include <hip/hip_fp16.h>

#define G_ 512
#define B_ 64
#define I_ 32
#define H_ 64
#define NGATE 256  // 4*H

typedef _Float16 half8 __attribute__((ext_vector_type(8)));
typedef _Float16 h4 __attribute__((ext_vector_type(4)));
typedef _Float16 h2 __attribute__((ext_vector_type(2)));
typedef float f32x4 __attribute__((ext_vector_type(4)));

#if __has_builtin(__builtin_amdgcn_fdot2)
#define FDOT2(a, b, c) __builtin_amdgcn_fdot2((a), (b), (c), false)
#else
#define FDOT2(a, b, c) ((c) + (float)(a)[0] * (float)(b)[0] + (float)(a)[1] * (float)(b)[1])
#endif

__device__ __forceinline__ float sigf(float x) {
  return 1.0f / (1.0f + __expf(-x));
}
__device__ __forceinline__ float tanh_fast(float x) {
  x = fminf(fmaxf(x, -15.0f), 15.0f);
  float e = __expf(2.0f * x);
  return (e - 1.0f) / (e + 1.0f);
}

// async global->LDS, 16 B per lane: LDS dest = wave-uniform base + lane*16,
// global src = per-lane pointer (guide m97: width-16 variant).
__device__ __forceinline__ void gload_lds16(const _Float16* g, _Float16* l) {
  __builtin_amdgcn_global_load_lds(
      (const __attribute__((address_space(1))) void*)g,
      (__attribute__((address_space(3))) void*)l, 16, 0, 0);
}

// ---------------- K1: xproj[b][g][col*4+q]  (coalesced; scan reads one h4/lane)
__global__ __launch_bounds__(256) void k_xproj(
    const float* __restrict__ input, const float* __restrict__ W_ih,
    const float* __restrict__ b_ih, const float* __restrict__ b_hh,
    _Float16* __restrict__ xproj) {
  const int g = blockIdx.x;
  const int t = threadIdx.x;
  const int col = t >> 2;
  const int q = t & 3;
  const int row = q * H_ + col;  // gate-row in torch i,f,g,o order
  __shared__ alignas(16) float inp[B_ * I_];
  const float* ing = input + (size_t)g * (B_ * I_);
#pragma unroll
  for (int u = 0; u < (B_ * I_) / 256; ++u) inp[u * 256 + t] = ing[u * 256 + t];
  float w[I_];
#pragma unroll
  for (int k = 0; k < I_; k += 4) {
    f32x4 v = *(const f32x4*)(W_ih + (size_t)row * I_ + k);
    w[k] = v[0]; w[k + 1] = v[1]; w[k + 2] = v[2]; w[k + 3] = v[3];
  }
  const float bias = b_ih[row] + b_hh[row];
  __syncthreads();
  for (int b = 0; b < B_; ++b) {
    float a0 = bias, a1 = 0.f, a2 = 0.f, a3 = 0.f;
#pragma unroll
    for (int k = 0; k < I_; k += 4) {
      f32x4 iv = *(const f32x4*)&inp[b * I_ + k];
      a0 += iv[0] * w[k]; a1 += iv[1] * w[k + 1];
      a2 += iv[2] * w[k + 2]; a3 += iv[3] * w[k + 3];
    }
    xproj[((size_t)b * G_ + g) * NGATE + t] = (_Float16)((a0 + a1) + (a2 + a3));
  }
}

// ---------------- R5-proven scan body (barrier-free, depth-8 xproj ring, f16 dots)
__device__ __forceinline__ void scan_row(
    int b, int j, const _Float16* __restrict__ xproj,
    const float* __restrict__ h0, const float* __restrict__ c0,
    const float* __restrict__ W_hh, _Float16* __restrict__ hs,
    _Float16* hsh) {
  h2 w[4][32];
#pragma unroll
  for (int q = 0; q < 4; ++q) {
    const f32x4* wr = (const f32x4*)(W_hh + (size_t)(q * H_ + j) * H_);
#pragma unroll
    for (int kk = 0; kk < 16; ++kk) {
      f32x4 v = wr[kk];
      h2 t0, t1;
      t0[0] = (_Float16)v[0]; t0[1] = (_Float16)v[1];
      t1[0] = (_Float16)v[2]; t1[1] = (_Float16)v[3];
      w[q][2 * kk] = t0;
      w[q][2 * kk + 1] = t1;
    }
  }
  float c = c0[b * H_ + j];
  hsh[j] = (_Float16)h0[b * H_ + j];

  const h4* xrow = (const h4*)(xproj + (size_t)b * G_ * NGATE) + j;
  h4 p[8];
#pragma unroll
  for (int d = 0; d < 8; ++d) p[d] = xrow[(size_t)d * 64];

  _Float16* hrow = hs + (size_t)b * (G_ * H_) + j;

  for (int g0 = 0; g0 < G_; g0 += 8) {
#pragma unroll
    for (int d = 0; d < 8; ++d) {
      const int g = g0 + d;
      float a[4], a2[4];
#pragma unroll
      for (int q = 0; q < 4; ++q) { a[q] = (float)p[d][q]; a2[q] = 0.0f; }
      const f32x4* hp4 = (const f32x4*)hsh;
#pragma unroll
      for (int k4 = 0; k4 < 4; ++k4) {
        f32x4 hv4 = hp4[k4];
#pragma unroll
        for (int t = 0; t < 4; ++t) {
          h2 hv = __builtin_bit_cast(h2, hv4[t]);
#pragma unroll
          for (int q = 0; q < 4; ++q) a[q] = FDOT2(hv, w[q][k4 * 4 + t], a[q]);
        }
      }
#pragma unroll
      for (int k4 = 4; k4 < 8; ++k4) {
        f32x4 hv4 = hp4[k4];
#pragma unroll
        for (int t = 0; t < 4; ++t) {
          h2 hv = __builtin_bit_cast(h2, hv4[t]);
#pragma unroll
          for (int q = 0; q < 4; ++q) a2[q] = FDOT2(hv, w[q][k4 * 4 + t], a2[q]);
        }
      }
#pragma unroll
      for (int q = 0; q < 4; ++q) a[q] += a2[q];

      float ig = sigf(a[0]);
      float fg = sigf(a[1]);
      float gg = tanh_fast(a[2]);
      float og = sigf(a[3]);
      c = fg * c + ig * gg;
      float hh = og * tanh_fast(c);
      _Float16 hf = (_Float16)hh;
      hsh[j] = hf;
      hrow[(size_t)g * H_] = hf;
      if (g + 8 < G_) p[d] = xrow[(size_t)(g + 8) * 64];
    }
  }
}

// ---------------- f32 -> f16 convert into TILE-LINEAR layout.
// Tile (nt, ksg) = rows nt*64..+63, k ksg*KWT..+KWT-1; tile bytes are the exact
// LDS image the GEMM wants (row rr at rr*KWT*2, XOR-swizzled 16-B slots), so
// the GEMM can stage with sequential global_load_lds. Reads are perfectly
// coalesced (source-linear); writes are >=256-B permuted runs.
template <int N, int K, int KWT>
__device__ __forceinline__ void conv_tiled(
    const float* __restrict__ src, _Float16* __restrict__ dst,
    int gtid, int gstride) {
  constexpr int ROWB = KWT * 2;
  constexpr int TILEH = 64 * KWT;  // halves per tile
  for (int i = gtid; i < N * (K / 8); i += gstride) {
    const int n = i / (K / 8);
    const int k8 = i % (K / 8);
    const f32x4* s = (const f32x4*)(src + (size_t)n * K + (size_t)k8 * 8);
    f32x4 v0 = s[0];
    f32x4 v1 = s[1];
    half8 h;
    h[0] = (_Float16)v0[0]; h[1] = (_Float16)v0[1];
    h[2] = (_Float16)v0[2]; h[3] = (_Float16)v0[3];
    h[4] = (_Float16)v1[0]; h[5] = (_Float16)v1[1];
    h[6] = (_Float16)v1[2]; h[7] = (_Float16)v1[3];
    const int nt = n >> 6, rr = n & 63;
    const int ksg = k8 / (KWT / 8);
    const int kk8 = k8 % (KWT / 8);
    const size_t tile_id = (size_t)nt * (K / KWT) + ksg;
    int byte = rr * ROWB + ((kk8 * 16) ^ ((rr & 7) << 4));
    *(half8*)((char*)(dst + tile_id * TILEH) + byte) = h;
  }
}

#define NCONV 2048  // R9-proven: 524K threads saturate HBM for the convert

// ---------------- K2: fused scan (blocks 0-63) + tiled weight convert (blocks 64+)
__global__ __launch_bounds__(256) void k_scan_conv(
    const _Float16* __restrict__ xproj, const float* __restrict__ h0,
    const float* __restrict__ c0, const float* __restrict__ W_hh,
    _Float16* __restrict__ hs,
    const float* __restrict__ W1, _Float16* __restrict__ W1h,
    const float* __restrict__ W2, _Float16* __restrict__ W2h,
    const float* __restrict__ W3, _Float16* __restrict__ W3h) {
  __shared__ alignas(16) _Float16 hsh[H_];
  const int bid = blockIdx.x;
  if (bid < B_) {
    if (threadIdx.x < 64)
      scan_row(bid, threadIdx.x, xproj, h0, c0, W_hh, hs, hsh);
    return;
  }
  const int gtid = (bid - B_) * 256 + threadIdx.x;
  const int gstride = NCONV * 256;
  conv_tiled<5120, 32768, 256>(W1, W1h, gtid, gstride);
  conv_tiled<2560, 5120, 128>(W2, W2h, gtid, gstride);
  conv_tiled<512, 2560, 128>(W3, W3h, gtid, gstride);
}

// ---------------- GEMM on tile-linear f16 weights with global_load_lds staging.
// Per stage: each wave issues CALLS sequential width-16 global_load_lds (1 KB
// each, no VGPR round-trip), then MFMA reads its own 16 rows from LDS.
template <int N, int K, int KC, int NTILES, int KW>
__global__ __launch_bounds__(256) void k_gemm_t(
    const _Float16* __restrict__ X, const _Float16* __restrict__ Wh,
    float* __restrict__ part) {
  constexpr int ROWB = KW * 2;
  constexpr int TILEB = 64 * ROWB;      // tile bytes (= LDS image)
  constexpr int WBYTES = TILEB / 4;     // bytes staged per wave
  constexpr int CALLS = WBYTES / 1024;  // 1 KB per global_load_lds per wave
  static_assert(KC % KW == 0, "stage divisibility");
  __shared__ alignas(16) _Float16 wl[TILEB / 2];
  const int bid = blockIdx.x;
  const int nt = bid % NTILES;
  const int ks = bid / NTILES;
  const int n0 = nt * 64;
  const int kbeg = ks * KC;
  const int lane = threadIdx.x & 63;
  const int wave = threadIdx.x >> 6;
  const int r = lane & 15;
  const int gq = lane >> 4;

  const _Float16* xrow = X + (size_t)r * K + kbeg + 8 * gq;
  f32x4 acc[4] = {};

  for (int st = 0; st < KC / KW; ++st) {
    const size_t tile_id = (size_t)nt * (K / KW) + (size_t)(kbeg / KW) + st;
    const _Float16* tile = Wh + tile_id * (TILEB / 2);
#pragma unroll
    for (int c = 0; c < CALLS; ++c) {
      const int uoff_h = (wave * WBYTES + c * 1024) / 2;  // wave-uniform
      gload_lds16(tile + uoff_h + lane * 8, wl + uoff_h);
    }
    __syncthreads();  // drains vmcnt(0): LDS tile complete
#pragma unroll
    for (int k32 = 0; k32 < KW; k32 += 32) {
      int rbyte = (wave * 16 + r) * ROWB + (k32 + 8 * gq) * 2;
      rbyte ^= (r & 7) << 4;
      half8 bfv = *(const half8*)((const char*)wl + rbyte);
      const _Float16* xp = xrow + st * KW + k32;
#pragma unroll
      for (int mi = 0; mi < 4; ++mi) {
        half8 af = *(const half8*)(xp + (size_t)(mi * 16) * K);
        acc[mi] = __builtin_amdgcn_mfma_f32_16x16x32_f16(af, bfv, acc[mi], 0, 0, 0);
      }
    }
    __syncthreads();
  }
#pragma unroll
  for (int mi = 0; mi < 4; ++mi) {
#pragma unroll
    for (int q = 0; q < 4; ++q) {
      int row = mi * 16 + gq * 4 + q;
      part[((size_t)ks * 64 + row) * N + n0 + wave * 16 + r] = acc[mi][q];
    }
  }
}

// ---------------- reduce k-split partials + bias -> f16 activations (x4 vectorized)
template <int N, int KS>
__global__ __launch_bounds__(256) void k_reduce(
    const float* __restrict__ part, const float* __restrict__ bias,
    _Float16* __restrict__ out) {
  const int idx4 = (blockIdx.x * 256 + threadIdx.x) * 4;
  const int n = idx4 % N;
  f32x4 s = *(const f32x4*)(bias + n);
#pragma unroll
  for (int ks = 0; ks < KS; ++ks) s += *(const f32x4*)(part + (size_t)ks * 64 * N + idx4);
#pragma unroll
  for (int t = 0; t < 4; ++t) out[idx4 + t] = (_Float16)s[t];
}

// ---------------- final reduce + bias + sigmoid -> fp32 output
template <int N, int KS>
__global__ __launch_bounds__(256) void k_reduce_sig(
    const float* __restrict__ part, const float* __restrict__ bias,
    float* __restrict__ out) {
  const int idx4 = (blockIdx.x * 256 + threadIdx.x) * 4;
  const int n = idx4 % N;
  f32x4 s = *(const f32x4*)(bias + n);
#pragma unroll
  for (int ks = 0; ks < KS; ++ks) s += *(const f32x4*)(part + (size_t)ks * 64 * N + idx4);
#pragma unroll
  for (int t = 0; t < 4; ++t) out[idx4 + t] = sigf(s[t]);
}

extern "C" void kernel_launch(void* const* d_in, const int* in_sizes, int n_in,
                              void* d_out, int out_size, void* d_ws, size_t ws_size,
                              hipStream_t stream) {
  const float* input = (const float*)d_in[0];
  const float* h0    = (const float*)d_in[1];
  const float* c0    = (const float*)d_in[2];
  const float* W_ih  = (const float*)d_in[3];
  const float* W_hh  = (const float*)d_in[4];
  const float* b_ih  = (const float*)d_in[5];
  const float* b_hh  = (const float*)d_in[6];
  const float* W1    = (const float*)d_in[7];
  const float* b1    = (const float*)d_in[8];
  const float* W2    = (const float*)d_in[9];
  const float* b2    = (const float*)d_in[10];
  const float* W3    = (const float*)d_in[11];
  const float* b3    = (const float*)d_in[12];
  float* out = (float*)d_out;

  // Workspace layout (~411.5 MB of ~2.6 GB):
  //   [0, 41943040)              part; xproj overlay (16.8 MB)
  //   [41943040, 46137344)       hs_f16  [64][32768]
  //   [46137344, 46792704)       x2_f16  [64][5120]
  //   [46792704, 47120384)       x3_f16  [64][2560]
  //   [47120384, 382664704)      W1h f16 tiled (5120x32768)
  //   [382664704, 408879104)     W2h f16 tiled (2560x5120)
  //   [408879104, 411500544)     W3h f16 tiled (512x2560)
  uint8_t* ws = (uint8_t*)d_ws;
  float*    part  = (float*)ws;
  _Float16* xproj = (_Float16*)ws;
  _Float16* hs    = (_Float16*)(ws + 41943040);
  _Float16* x2    = (_Float16*)(ws + 46137344);
  _Float16* x3    = (_Float16*)(ws + 46792704);
  _Float16* W1h   = (_Float16*)(ws + 47120384);
  _Float16* W2h   = (_Float16*)(ws + 382664704);
  _Float16* W3h   = (_Float16*)(ws + 408879104);

  k_xproj<<<G_, 256, 0, stream>>>(input, W_ih, b_ih, b_hh, xproj);
  // Fused: blocks 0-63 = R5 scan; blocks 64.. = tiled f32->f16 convert
  k_scan_conv<<<B_ + NCONV, 256, 0, stream>>>(xproj, h0, c0, W_hh, hs,
                                              W1, W1h, W2, W2h, W3, W3h);
  // GEMM1: [64,32768] x W1h[5120,32768]^T, ksplit=32 (KC=1024), KW=256
  k_gemm_t<5120, 32768, 1024, 80, 256><<<80 * 32, 256, 0, stream>>>(hs, W1h, part);
  k_reduce<5120, 32><<<(64 * 5120) / 4 / 256, 256, 0, stream>>>(part, b1, x2);
  // GEMM2: [64,5120] x W2h[2560,5120]^T, ksplit=8 (KC=640), KW=128
  k_gemm_t<2560, 5120, 640, 40, 128><<<40 * 8, 256, 0, stream>>>(x2, W2h, part);
  k_reduce<2560, 8><<<(64 * 2560) / 4 / 256, 256, 0, stream>>>(part, b2, x3);
  // GEMM3: [64,2560] x W3h[512,2560]^T, ksplit=10 (KC=256), KW=128
  k_gemm_t<512, 2560, 256, 8, 128><<<8 * 10, 256, 0, stream>>>(x3, W3h, part);
  k_reduce_sig<512, 10><<<(64 * 512) / 4 / 256, 256, 0, stream>>>(part, b3, out);
}